// Round 1
// baseline (912.374 us; speedup 1.0000x reference)
//
#include <hip/hip_runtime.h>
#include <hip/hip_bf16.h>
#include <math.h>

#define N_BATCH 128
#define C_CH    512
#define HF      38
#define WF      38
#define K1      25088   // 512*49
#define NH      4096
#define NCLS    21
#define NBOX    80

// ---------------------------------------------------------------------------
// Kernel 1: ROI crop + adaptive 7x7 maxpool.
// crop[n,ch,y,x'] = x[n, ch, c+y, r+x']; pool cell (i,j) covers rows
// [i*h/7, ceil((i+1)h/7)) x cols [j*w/7, ceil((j+1)w/7)). Only rows<h, cols<w
// are ever read, so we stage just the h x w valid region in LDS.
// flat[n][ch*49 + i*7 + j] row-major (k contiguous) for GEMM1 A-operand.
// ---------------------------------------------------------------------------
__global__ __launch_bounds__(256) void pool_kernel(
    const float* __restrict__ x, const int* __restrict__ rp,
    float* __restrict__ flat) {
  const int n  = blockIdx.y;
  const int cb = blockIdx.x;      // 8 channels per block
  const int tid = threadIdx.x;
  const int r = rp[n*4+0], c = rp[n*4+1], w = rp[n*4+2], h = rp[n*4+3];
  __shared__ float tile[8][24][25];
  const float* xb = x + (((size_t)(n*C_CH + cb*8))*HF + c)*WF + r;
  const int hw = h*w;
  #pragma unroll
  for (int ch = 0; ch < 8; ++ch) {
    const float* xc = xb + (size_t)ch*HF*WF;
    for (int idx = tid; idx < hw; idx += 256) {
      int y  = idx / w;
      int xx = idx - y*w;
      tile[ch][y][xx] = xc[y*WF + xx];
    }
  }
  __syncthreads();
  for (int o = tid; o < 8*49; o += 256) {
    int ch = o / 49, ij = o - ch*49, i = ij / 7, j = ij - i*7;
    int rs = (i*h)/7, re = ((i+1)*h + 6)/7;
    int cs = (j*w)/7, ce = ((j+1)*w + 6)/7;
    float m = -INFINITY;
    for (int y = rs; y < re; ++y)
      for (int xx = cs; xx < ce; ++xx)
        m = fmaxf(m, tile[ch][y][xx]);
    flat[(size_t)n*K1 + (cb*8+ch)*49 + ij] = m;
  }
}

// ---------------------------------------------------------------------------
// Kernel 2: fp32 split-K GEMM.  C_part[ks] = A[:, kchunk]@B[kchunk, :]
// BM=128 (whole batch) x BN=128 x BK=16, 256 threads (16x16), 8x8 micro-tile.
// B-tile LDS uses a float4-block XOR swizzle (m ^= (m>>3)&3) so the stride-8
// column reads hit each bank pair exactly 2x (2-way is free on CDNA4).
// ---------------------------------------------------------------------------
template<int KS>
__global__ __launch_bounds__(256) void gemm_splitk(
    const float* __restrict__ A, const float* __restrict__ B,
    float* __restrict__ part, int K, int Nn) {
  const int nb   = blockIdx.x;
  const int ksid = blockIdx.y;
  const int tid  = threadIdx.x;
  const int tx = tid & 15, ty = tid >> 4;
  __shared__ float As[16][132];   // [k][m], +4 pad
  __shared__ float Bs[16][128];   // [k][n], swizzled float4 blocks
  float acc[8][8];
  #pragma unroll
  for (int i = 0; i < 8; ++i)
    #pragma unroll
    for (int j = 0; j < 8; ++j) acc[i][j] = 0.f;

  const int kchunk = K / KS;
  const int k0 = ksid * kchunk;
  const int am = tid >> 1, ak = (tid & 1) * 8;       // A staging: row am, k ak..ak+7
  const int bk = tid >> 4, bn = (tid & 15) * 8;      // B staging: k bk, cols bn..bn+7
  const int m0  = bn >> 2;
  const int wb0 = (m0 ^ ((m0 >> 3) & 3)) * 4;
  const int m1  = m0 + 1;
  const int wb1 = (m1 ^ ((m1 >> 3) & 3)) * 4;
  const int r0 = tx*2, r1 = tx*2 + 1;
  const int rb0 = (r0 ^ ((r0 >> 3) & 3)) * 4;
  const int rb1 = (r1 ^ ((r1 >> 3) & 3)) * 4;
  const float* Aptr = A + (size_t)am * K + k0 + ak;
  const float* Bptr = B + ((size_t)(k0 + bk)) * Nn + (size_t)nb * 128 + bn;

  for (int kt = 0; kt < kchunk; kt += 16) {
    const float4 a0 = *(const float4*)(Aptr + kt);
    const float4 a1 = *(const float4*)(Aptr + kt + 4);
    const float4 b0 = *(const float4*)(Bptr + (size_t)kt * Nn);
    const float4 b1 = *(const float4*)(Bptr + (size_t)kt * Nn + 4);
    __syncthreads();
    As[ak+0][am]=a0.x; As[ak+1][am]=a0.y; As[ak+2][am]=a0.z; As[ak+3][am]=a0.w;
    As[ak+4][am]=a1.x; As[ak+5][am]=a1.y; As[ak+6][am]=a1.z; As[ak+7][am]=a1.w;
    *(float4*)&Bs[bk][wb0] = b0;
    *(float4*)&Bs[bk][wb1] = b1;
    __syncthreads();
    #pragma unroll
    for (int kk = 0; kk < 16; ++kk) {
      float a[8], b[8];
      *(float4*)&a[0] = *(const float4*)&As[kk][ty*8];
      *(float4*)&a[4] = *(const float4*)&As[kk][ty*8 + 4];
      *(float4*)&b[0] = *(const float4*)&Bs[kk][rb0];
      *(float4*)&b[4] = *(const float4*)&Bs[kk][rb1];
      #pragma unroll
      for (int i = 0; i < 8; ++i)
        #pragma unroll
        for (int j = 0; j < 8; ++j)
          acc[i][j] = fmaf(a[i], b[j], acc[i][j]);
    }
  }
  float* P = part + (size_t)ksid * N_BATCH * Nn + (size_t)nb * 128;
  #pragma unroll
  for (int i = 0; i < 8; ++i) {
    *(float4*)&P[(size_t)(ty*8+i)*Nn + tx*8]     = *(float4*)&acc[i][0];
    *(float4*)&P[(size_t)(ty*8+i)*Nn + tx*8 + 4] = *(float4*)&acc[i][4];
  }
}

// ---------------------------------------------------------------------------
// Kernel 3: reduce split-K partials + bias + relu  (deterministic order)
// ---------------------------------------------------------------------------
template<int KS>
__global__ __launch_bounds__(256) void reduce_bias_relu(
    const float* __restrict__ part, const float* __restrict__ bias,
    float* __restrict__ out, int Nn) {
  const int idx = blockIdx.x * 256 + threadIdx.x;   // float4 index
  const int total = N_BATCH * Nn / 4;
  if (idx >= total) return;
  float4 s = ((const float4*)part)[idx];
  #pragma unroll
  for (int ks = 1; ks < KS; ++ks) {
    float4 p = ((const float4*)part)[(size_t)ks * total + idx];
    s.x += p.x; s.y += p.y; s.z += p.z; s.w += p.w;
  }
  const int n4 = idx & (Nn/4 - 1);
  float4 bv = ((const float4*)bias)[n4];
  s.x = fmaxf(s.x + bv.x, 0.f);
  s.y = fmaxf(s.y + bv.y, 0.f);
  s.z = fmaxf(s.z + bv.z, 0.f);
  s.w = fmaxf(s.w + bv.w, 0.f);
  ((float4*)out)[idx] = s;
}

// ---------------------------------------------------------------------------
// Kernel 4: head — h2@Wcls (softmax) and h2@Wbox (bbox transform).
// One block per batch row; h2 row staged in LDS; lanes 0..20 -> cls cols,
// lanes 21..100 -> box cols. Bbox math uses non-fused mul/add to match the
// reference's separate-op semantics through ceil/floor discontinuities.
// ---------------------------------------------------------------------------
__global__ __launch_bounds__(128) void head_kernel(
    const float* __restrict__ h2, const float* __restrict__ Wcls,
    const float* __restrict__ Wbox, const int* __restrict__ rp,
    float* __restrict__ out) {
  const int n = blockIdx.x;
  const int tid = threadIdx.x;
  __shared__ float h2s[NH];
  __shared__ float logits[NCLS];
  __shared__ float red[2];
  for (int k = tid; k < NH; k += 128) h2s[k] = h2[(size_t)n*NH + k];
  __syncthreads();
  const bool is_cls = tid < NCLS;
  const bool is_box = (tid >= NCLS) && (tid < NCLS + NBOX);
  const float* W = is_cls ? (Wcls + tid) : (is_box ? (Wbox + (tid - NCLS)) : Wcls);
  const int stride = is_cls ? NCLS : (is_box ? NBOX : 0);
  float s0=0.f, s1=0.f, s2=0.f, s3=0.f;
  for (int k = 0; k < NH; k += 4) {
    s0 = fmaf(h2s[k+0], W[(size_t)(k+0)*stride], s0);
    s1 = fmaf(h2s[k+1], W[(size_t)(k+1)*stride], s1);
    s2 = fmaf(h2s[k+2], W[(size_t)(k+2)*stride], s2);
    s3 = fmaf(h2s[k+3], W[(size_t)(k+3)*stride], s3);
  }
  const float acc = (s0 + s1) + (s2 + s3);
  if (is_cls) logits[tid] = acc;
  __syncthreads();
  if (tid == 0) {
    float m = logits[0];
    for (int i = 1; i < NCLS; ++i) m = fmaxf(m, logits[i]);
    float s = 0.f;
    for (int i = 0; i < NCLS; ++i) s += expf(logits[i] - m);
    red[0] = m; red[1] = s;
  }
  __syncthreads();
  if (is_cls) {
    out[(size_t)n*NCLS + tid] = expf(logits[tid] - red[0]) / red[1];
  } else if (is_box) {
    const int j = tid - NCLS;
    const float t  = acc;
    const float rf = (float)rp[n*4+0];
    const float cf = (float)rp[n*4+1];
    const float wf = (float)rp[n*4+2];
    const float hf = (float)rp[n*4+3];
    float p;
    switch (j & 3) {
      case 0:  p = ceilf (__fmul_rn(__fadd_rn(__fmul_rn(wf, t), rf), 16.f)) - 1.f; break;
      case 1:  p = ceilf (__fmul_rn(__fadd_rn(__fmul_rn(hf, t), cf), 16.f)) - 1.f; break;
      case 2:  p = floorf(__fmul_rn(__fmul_rn(wf, expf(t)), 16.f)) + 1.f; break;
      default: p = floorf(__fmul_rn(__fmul_rn(hf, expf(t)), 16.f)) + 1.f; break;
    }
    out[(size_t)N_BATCH*NCLS + (size_t)n*NBOX + j] = p;
  }
}

// ---------------------------------------------------------------------------
extern "C" void kernel_launch(void* const* d_in, const int* in_sizes, int n_in,
                              void* d_out, int out_size, void* d_ws, size_t ws_size,
                              hipStream_t stream) {
  const float* x    = (const float*)d_in[0];
  const int*   rp   = (const int*)  d_in[1];
  const float* W1   = (const float*)d_in[2];
  const float* b1   = (const float*)d_in[3];
  const float* W2   = (const float*)d_in[4];
  const float* b2   = (const float*)d_in[5];
  const float* Wcls = (const float*)d_in[6];
  const float* Wbox = (const float*)d_in[7];
  float* out = (float*)d_out;

  // workspace layout (floats): flat | h1 | h2 | partials(8 x 128 x 4096)
  float* ws   = (float*)d_ws;
  float* flat = ws;                                  // 3,211,264
  float* h1   = flat + (size_t)N_BATCH*K1;           //   524,288
  float* h2   = h1   + (size_t)N_BATCH*NH;           //   524,288
  float* part = h2   + (size_t)N_BATCH*NH;           // 4,194,304  (~33.8 MB total)

  pool_kernel<<<dim3(64, 128), 256, 0, stream>>>(x, rp, flat);

  gemm_splitk<8><<<dim3(32, 8), 256, 0, stream>>>(flat, W1, part, K1, NH);
  reduce_bias_relu<8><<<dim3(512), 256, 0, stream>>>(part, b1, h1, NH);

  gemm_splitk<8><<<dim3(32, 8), 256, 0, stream>>>(h1, W2, part, NH, NH);
  reduce_bias_relu<8><<<dim3(512), 256, 0, stream>>>(part, b2, h2, NH);

  head_kernel<<<dim3(128), 128, 0, stream>>>(h2, Wcls, Wbox, rp, out);
}

// Round 2
// 709.603 us; speedup vs baseline: 1.2858x; 1.2858x over previous
//
#include <hip/hip_runtime.h>
#include <hip/hip_bf16.h>
#include <math.h>

#define N_BATCH 128
#define C_CH    512
#define HF      38
#define WF      38
#define K1      25088   // 512*49
#define NH      4096
#define NCLS    21
#define NBOX    80
#define STEPS1  784     // K1/32
#define STEPS2  128     // NH/32

typedef __attribute__((ext_vector_type(8))) short s16x8;
typedef __attribute__((ext_vector_type(4))) float f32x4;

// ---------------------------------------------------------------------------
// fp32 -> 3x bf16 split (RNE), exact residuals in fp32.
// x ~= b0 + b1 + b2 with |residual| <~ |x|*2^-25.
// ---------------------------------------------------------------------------
__device__ __forceinline__ unsigned short bf_rne(float x) {
  unsigned u = __float_as_uint(x);
  return (unsigned short)((u + 0x7FFFu + ((u >> 16) & 1u)) >> 16);
}
__device__ __forceinline__ float bf2f(unsigned short b) {
  return __uint_as_float(((unsigned)b) << 16);
}
__device__ __forceinline__ void split3(float x, unsigned short& q0,
                                       unsigned short& q1, unsigned short& q2) {
  q0 = bf_rne(x); float r1 = x - bf2f(q0);
  q1 = bf_rne(r1); float r2 = r1 - bf2f(q1);
  q2 = bf_rne(r2);
}

__device__ __forceinline__ void gload16(const void* g, void* l) {
  __builtin_amdgcn_global_load_lds(
      (const __attribute__((address_space(1))) unsigned int*)g,
      (__attribute__((address_space(3))) unsigned int*)l, 16, 0, 0);
}

// ---------------------------------------------------------------------------
// Kernel 1: ROI crop + adaptive 7x7 maxpool, writing A as 3 bf16 planes in
// MFMA-fragment-swizzled layout:
//   step chunk S (32 k's) = 24576 B: [plane p][m-tile mt][lane l][e] where
//   lane = ((k>>3)&3)*16 + (m&15), e = k&7, mt = m>>4.
// ---------------------------------------------------------------------------
__global__ __launch_bounds__(256) void pool_kernel(
    const float* __restrict__ x, const int* __restrict__ rp,
    unsigned short* __restrict__ Asw) {
  const int n = blockIdx.y, cb = blockIdx.x, tid = threadIdx.x;
  const int r = rp[n*4+0], c = rp[n*4+1], w = rp[n*4+2], h = rp[n*4+3];
  __shared__ float tile[8][24][25];
  const float* xb = x + (((size_t)(n*C_CH + cb*8))*HF + c)*WF + r;
  const int hw = h*w;
  #pragma unroll
  for (int ch = 0; ch < 8; ++ch) {
    const float* xc = xb + (size_t)ch*HF*WF;
    for (int idx = tid; idx < hw; idx += 256) {
      int y = idx / w, xx = idx - y*w;
      tile[ch][y][xx] = xc[y*WF + xx];
    }
  }
  __syncthreads();
  const int mt = n >> 4, mlo = n & 15;
  for (int o = tid; o < 8*49; o += 256) {
    int ch = o / 49, ij = o - ch*49, i = ij / 7, j = ij - i*7;
    int rs = (i*h)/7, re = ((i+1)*h + 6)/7;
    int cs = (j*w)/7, ce = ((j+1)*w + 6)/7;
    float m = -INFINITY;
    for (int y = rs; y < re; ++y)
      for (int xx = cs; xx < ce; ++xx)
        m = fmaxf(m, tile[ch][y][xx]);
    int k = (cb*8 + ch)*49 + ij;
    int S = k >> 5, g = (k >> 3) & 3, e = k & 7;
    size_t base = (size_t)S*12288 + (size_t)mt*512 + (size_t)(g*16 + mlo)*8 + e;
    unsigned short q0, q1, q2; split3(m, q0, q1, q2);
    Asw[base] = q0; Asw[base + 4096] = q1; Asw[base + 8192] = q2;
  }
}

// ---------------------------------------------------------------------------
// Kernel 2: split-K MFMA GEMM.  part[ks] += Asw(k-chunk) @ B(k-chunk,:)
// BM=128 (whole batch), BN=256, BK=32. 256 threads = 4 waves; wave wv owns
// n in [wv*64, wv*64+64): 8 m-tiles x 4 n-tiles of 16x16, acc = 128 f32/lane.
// A: pre-split bf16 planes staged linearly via global_load_lds (frag order).
// B: fp32 staged to padded LDS [32][258] (2-way banks = free), split 3-way
// in-register once per element per wave; 6 MFMA products per (mt,nt).
// ---------------------------------------------------------------------------
__global__ __launch_bounds__(256, 2) void gemm_mfma(
    const unsigned short* __restrict__ Asw, const float* __restrict__ B,
    float* __restrict__ part, const int nsteps) {
  extern __shared__ char smem[];
  unsigned short* Asm = (unsigned short*)smem;      // 24576 B
  float* Bsm = (float*)(smem + 24576);              // 32*258*4 = 33024 B
  const int tid = threadIdx.x, lane = tid & 63, wv = tid >> 6;
  const int nb = blockIdx.x, ks = blockIdx.y;
  const int l15 = lane & 15, g = lane >> 4;
  const unsigned short* Ab = Asw + (size_t)ks * nsteps * 12288;
  const float* Bb = B + ((size_t)ks * nsteps * 32) * NH + (size_t)nb * 256;

  f32x4 acc[8][4];
  #pragma unroll
  for (int i = 0; i < 8; ++i)
    #pragma unroll
    for (int j = 0; j < 4; ++j) acc[i][j] = (f32x4){0.f, 0.f, 0.f, 0.f};

  for (int s = 0; s < nsteps; ++s) {
    __syncthreads();   // previous compute done before restaging
    const char* As_g = (const char*)(Ab + (size_t)s*12288);
    const float* Bs_g = Bb + (size_t)s*32*NH;
    #pragma unroll
    for (int i = 0; i < 14; ++i) {
      int cch = wv*14 + i;                 // 24 A-chunks + 32 B-rows = 56
      if (cch < 24) {
        gload16(As_g + (size_t)cch*1024 + lane*16, (char*)Asm + cch*1024);
      } else {
        int row = cch - 24;
        gload16((const char*)(Bs_g + (size_t)row*NH) + lane*16,
                (char*)(Bsm + row*258));
      }
    }
    asm volatile("s_waitcnt vmcnt(0)" ::: "memory");
    __syncthreads();

    // B fragments: lane holds B[k=g*8+e][wv*64+nt*16+l15], split 3-way
    s16x8 bf[3][4];
    #pragma unroll
    for (int nt = 0; nt < 4; ++nt) {
      unsigned short q0[8], q1[8], q2[8];
      #pragma unroll
      for (int e = 0; e < 8; ++e) {
        float xv = Bsm[(g*8 + e)*258 + wv*64 + nt*16 + l15];
        split3(xv, q0[e], q1[e], q2[e]);
      }
      #pragma unroll
      for (int e = 0; e < 8; ++e) {
        bf[0][nt][e] = (short)q0[e];
        bf[1][nt][e] = (short)q1[e];
        bf[2][nt][e] = (short)q2[e];
      }
    }
    #pragma unroll
    for (int mt = 0; mt < 8; ++mt) {
      const s16x8 a0 = *(const s16x8*)(Asm +        mt*512 + lane*8);
      const s16x8 a1 = *(const s16x8*)(Asm + 4096 + mt*512 + lane*8);
      const s16x8 a2 = *(const s16x8*)(Asm + 8192 + mt*512 + lane*8);
      #pragma unroll
      for (int nt = 0; nt < 4; ++nt) {
        f32x4 cc = acc[mt][nt];
        cc = __builtin_amdgcn_mfma_f32_16x16x32_bf16(a0, bf[0][nt], cc, 0, 0, 0);
        cc = __builtin_amdgcn_mfma_f32_16x16x32_bf16(a0, bf[1][nt], cc, 0, 0, 0);
        cc = __builtin_amdgcn_mfma_f32_16x16x32_bf16(a1, bf[0][nt], cc, 0, 0, 0);
        cc = __builtin_amdgcn_mfma_f32_16x16x32_bf16(a0, bf[2][nt], cc, 0, 0, 0);
        cc = __builtin_amdgcn_mfma_f32_16x16x32_bf16(a1, bf[1][nt], cc, 0, 0, 0);
        cc = __builtin_amdgcn_mfma_f32_16x16x32_bf16(a2, bf[0][nt], cc, 0, 0, 0);
        acc[mt][nt] = cc;
      }
    }
  }
  // epilogue: C/D layout row=(lane>>4)*4+r, col=lane&15
  float* Pb = part + (size_t)ks*N_BATCH*NH + (size_t)nb*256 + wv*64;
  #pragma unroll
  for (int mt = 0; mt < 8; ++mt)
    #pragma unroll
    for (int nt = 0; nt < 4; ++nt)
      #pragma unroll
      for (int rr = 0; rr < 4; ++rr)
        Pb[(size_t)(mt*16 + g*4 + rr)*NH + nt*16 + l15] = acc[mt][nt][rr];
}

// ---------------------------------------------------------------------------
// Kernel 3: reduce split-K partials + bias + relu.
// mode 0: write swizzled bf16 planes (A for next GEMM). mode 1: write fp32.
// ---------------------------------------------------------------------------
__global__ __launch_bounds__(256) void reduce_k(
    const float* __restrict__ part, const float* __restrict__ bias,
    unsigned short* __restrict__ Asw2, float* __restrict__ f32out,
    int KS, int mode) {
  const int idx = blockIdx.x*256 + threadIdx.x;     // float4 idx, 131072 total
  float4 sA = ((const float4*)part)[idx];
  for (int k2 = 1; k2 < KS; ++k2) {
    float4 p = ((const float4*)part)[(size_t)k2*131072 + idx];
    sA.x += p.x; sA.y += p.y; sA.z += p.z; sA.w += p.w;
  }
  float4 bv = ((const float4*)bias)[idx & 1023];
  float v[4];
  v[0] = fmaxf(sA.x + bv.x, 0.f); v[1] = fmaxf(sA.y + bv.y, 0.f);
  v[2] = fmaxf(sA.z + bv.z, 0.f); v[3] = fmaxf(sA.w + bv.w, 0.f);
  if (mode == 1) {
    float4 o; o.x = v[0]; o.y = v[1]; o.z = v[2]; o.w = v[3];
    ((float4*)f32out)[idx] = o;
  } else {
    int m = idx >> 10, k = (idx & 1023) * 4;
    int S = k >> 5, g = (k >> 3) & 3, e0 = k & 7;
    size_t base = (size_t)S*12288 + (size_t)(m >> 4)*512
                + (size_t)(g*16 + (m & 15))*8 + e0;
    unsigned short q[3][4];
    #pragma unroll
    for (int e = 0; e < 4; ++e) split3(v[e], q[0][e], q[1][e], q[2][e]);
    #pragma unroll
    for (int p = 0; p < 3; ++p) {
      ushort4 st; st.x = q[p][0]; st.y = q[p][1]; st.z = q[p][2]; st.w = q[p][3];
      *(ushort4*)(Asw2 + base + p*4096) = st;
    }
  }
}

// ---------------------------------------------------------------------------
// Kernel 4: head — h2@Wcls (softmax) and h2@Wbox (bbox transform).
// ---------------------------------------------------------------------------
__global__ __launch_bounds__(128) void head_kernel(
    const float* __restrict__ h2, const float* __restrict__ Wcls,
    const float* __restrict__ Wbox, const int* __restrict__ rp,
    float* __restrict__ out) {
  const int n = blockIdx.x;
  const int tid = threadIdx.x;
  __shared__ float h2s[NH];
  __shared__ float logits[NCLS];
  __shared__ float red[2];
  for (int k = tid; k < NH; k += 128) h2s[k] = h2[(size_t)n*NH + k];
  __syncthreads();
  const bool is_cls = tid < NCLS;
  const bool is_box = (tid >= NCLS) && (tid < NCLS + NBOX);
  const float* W = is_cls ? (Wcls + tid) : (is_box ? (Wbox + (tid - NCLS)) : Wcls);
  const int stride = is_cls ? NCLS : (is_box ? NBOX : 0);
  float s0=0.f, s1=0.f, s2=0.f, s3=0.f;
  for (int k = 0; k < NH; k += 4) {
    s0 = fmaf(h2s[k+0], W[(size_t)(k+0)*stride], s0);
    s1 = fmaf(h2s[k+1], W[(size_t)(k+1)*stride], s1);
    s2 = fmaf(h2s[k+2], W[(size_t)(k+2)*stride], s2);
    s3 = fmaf(h2s[k+3], W[(size_t)(k+3)*stride], s3);
  }
  const float acc = (s0 + s1) + (s2 + s3);
  if (is_cls) logits[tid] = acc;
  __syncthreads();
  if (tid == 0) {
    float m = logits[0];
    for (int i = 1; i < NCLS; ++i) m = fmaxf(m, logits[i]);
    float s = 0.f;
    for (int i = 0; i < NCLS; ++i) s += expf(logits[i] - m);
    red[0] = m; red[1] = s;
  }
  __syncthreads();
  if (is_cls) {
    out[(size_t)n*NCLS + tid] = expf(logits[tid] - red[0]) / red[1];
  } else if (is_box) {
    const int j = tid - NCLS;
    const float t  = acc;
    const float rf = (float)rp[n*4+0];
    const float cf = (float)rp[n*4+1];
    const float wf = (float)rp[n*4+2];
    const float hf = (float)rp[n*4+3];
    float p;
    switch (j & 3) {
      case 0:  p = ceilf (__fmul_rn(__fadd_rn(__fmul_rn(wf, t), rf), 16.f)) - 1.f; break;
      case 1:  p = ceilf (__fmul_rn(__fadd_rn(__fmul_rn(hf, t), cf), 16.f)) - 1.f; break;
      case 2:  p = floorf(__fmul_rn(__fmul_rn(wf, expf(t)), 16.f)) + 1.f; break;
      default: p = floorf(__fmul_rn(__fmul_rn(hf, expf(t)), 16.f)) + 1.f; break;
    }
    out[(size_t)N_BATCH*NCLS + (size_t)n*NBOX + j] = p;
  }
}

// ---------------------------------------------------------------------------
extern "C" void kernel_launch(void* const* d_in, const int* in_sizes, int n_in,
                              void* d_out, int out_size, void* d_ws, size_t ws_size,
                              hipStream_t stream) {
  const float* x    = (const float*)d_in[0];
  const int*   rp   = (const int*)  d_in[1];
  const float* W1   = (const float*)d_in[2];
  const float* b1   = (const float*)d_in[3];
  const float* W2   = (const float*)d_in[4];
  const float* b2   = (const float*)d_in[5];
  const float* Wcls = (const float*)d_in[6];
  const float* Wbox = (const float*)d_in[7];
  float* out = (float*)d_out;

  // ws layout: Asw1 (19.27MB) | Asw2 (3.15MB) | h2 (2.1MB) | partials (KS1*2MB)
  char* wp = (char*)d_ws;
  unsigned short* Asw1 = (unsigned short*)wp;  wp += (size_t)STEPS1 * 24576;
  unsigned short* Asw2 = (unsigned short*)wp;  wp += (size_t)STEPS2 * 24576;
  float* h2 = (float*)wp;                      wp += (size_t)N_BATCH * NH * 4;
  float* part = (float*)wp;

  const size_t fixed = (size_t)STEPS1*24576 + (size_t)STEPS2*24576
                     + (size_t)N_BATCH*NH*4;
  const size_t slab = (size_t)N_BATCH * NH * 4;  // 2 MB per split-K partial
  int KS1 = 28;                                  // 784 = 28*28 steps
  if (fixed + 28*slab > ws_size) KS1 = 16;
  if (fixed + (size_t)KS1*slab > ws_size) KS1 = 8;
  if (fixed + (size_t)KS1*slab > ws_size) KS1 = 4;
  const int KS2 = (KS1 >= 16) ? 16 : KS1;        // 128 steps divisible by all

  pool_kernel<<<dim3(64, 128), 256, 0, stream>>>(x, rp, Asw1);

  gemm_mfma<<<dim3(16, KS1), 256, 57600, stream>>>(Asw1, W1, part, STEPS1/KS1);
  reduce_k<<<dim3(512), 256, 0, stream>>>(part, b1, Asw2, nullptr, KS1, 0);

  gemm_mfma<<<dim3(16, KS2), 256, 57600, stream>>>(Asw2, W2, part, STEPS2/KS2);
  reduce_k<<<dim3(512), 256, 0, stream>>>(part, b2, nullptr, h2, KS2, 1);

  head_kernel<<<dim3(128), 128, 0, stream>>>(h2, Wcls, Wbox, rp, out);
}

// Round 3
// 563.955 us; speedup vs baseline: 1.6178x; 1.2583x over previous
//
#include <hip/hip_runtime.h>
#include <hip/hip_bf16.h>
#include <math.h>

#define N_BATCH 128
#define C_CH    512
#define HF      38
#define WF      38
#define K1      25088   // 512*49
#define NH      4096
#define NCLS    21
#define NBOX    80
#define STEPS1  784     // K1/32
#define STEPS2  128     // NH/32

typedef __attribute__((ext_vector_type(8))) short s16x8;
typedef __attribute__((ext_vector_type(4))) float f32x4;

// fp32 -> 3x bf16 split (RNE): x ~= b0+b1+b2, residual ~ |x|*2^-25
__device__ __forceinline__ unsigned short bf_rne(float x) {
  unsigned u = __float_as_uint(x);
  return (unsigned short)((u + 0x7FFFu + ((u >> 16) & 1u)) >> 16);
}
__device__ __forceinline__ float bf2f(unsigned short b) {
  return __uint_as_float(((unsigned)b) << 16);
}
__device__ __forceinline__ void split3(float x, unsigned short& q0,
                                       unsigned short& q1, unsigned short& q2) {
  q0 = bf_rne(x); float r1 = x - bf2f(q0);
  q1 = bf_rne(r1); float r2 = r1 - bf2f(q1);
  q2 = bf_rne(r2);
}

__device__ __forceinline__ void gload16(const void* g, void* l) {
  __builtin_amdgcn_global_load_lds(
      (const __attribute__((address_space(1))) unsigned int*)g,
      (__attribute__((address_space(3))) unsigned int*)l, 16, 0, 0);
}

// ---------------------------------------------------------------------------
// Kernel 1: ROI crop + adaptive 7x7 maxpool -> flat fp32 [128][K1]
// thread t: ch = t>>5 (8 channels/block), lane32 = t&31 strides cols (no
// integer divide, coalesced 32-lane row reads).
// ---------------------------------------------------------------------------
__global__ __launch_bounds__(256) void pool_kernel(
    const float* __restrict__ x, const int* __restrict__ rp,
    float* __restrict__ flat) {
  const int n = blockIdx.y, cb = blockIdx.x, tid = threadIdx.x;
  const int r = rp[n*4+0], c = rp[n*4+1], w = rp[n*4+2], h = rp[n*4+3];
  __shared__ float tile[8][24][25];
  const int ch = tid >> 5, l32 = tid & 31;
  const float* xc = x + (((size_t)(n*C_CH + cb*8 + ch))*HF + c)*WF + r;
  for (int y = 0; y < h; ++y)
    for (int xx = l32; xx < w; xx += 32)
      tile[ch][y][xx] = xc[y*WF + xx];
  __syncthreads();
  for (int o = tid; o < 8*49; o += 256) {
    int ch2 = o / 49, ij = o - ch2*49, i = ij / 7, j = ij - i*7;
    int rs = (i*h)/7, re = ((i+1)*h + 6)/7;
    int cs = (j*w)/7, ce = ((j+1)*w + 6)/7;
    float m = -INFINITY;
    for (int y = rs; y < re; ++y)
      for (int xx = cs; xx < ce; ++xx)
        m = fmaxf(m, tile[ch2][y][xx]);
    flat[(size_t)n*K1 + (cb*8+ch2)*49 + ij] = m;
  }
}

// ---------------------------------------------------------------------------
// Kernel 2: fp32 [128][ld] -> 3 bf16 planes in MFMA fragment order.
// Step chunk S: 12288 shorts: [plane p][mt][g*16+mlo][e]; contiguous 16B
// writes per (p,g), fully dense per block.
// ---------------------------------------------------------------------------
__global__ __launch_bounds__(256) void convert_kernel(
    const float* __restrict__ flat, unsigned short* __restrict__ Asw, int ld) {
  const int S = blockIdx.x, t = threadIdx.x;
  const int mt = t >> 5, g2 = (t >> 4) & 1, mlo = t & 15;
  #pragma unroll
  for (int gg = 0; gg < 2; ++gg) {
    const int g = g2 + gg*2;
    const float* src = flat + (size_t)(mt*16 + mlo)*ld + S*32 + g*8;
    float v[8];
    *(float4*)&v[0] = *(const float4*)src;
    *(float4*)&v[4] = *(const float4*)(src + 4);
    unsigned short q[3][8];
    #pragma unroll
    for (int e = 0; e < 8; ++e) split3(v[e], q[0][e], q[1][e], q[2][e]);
    size_t base = (size_t)S*12288 + mt*512 + (size_t)(g*16 + mlo)*8;
    #pragma unroll
    for (int p = 0; p < 3; ++p) {
      ushort4 lo; lo.x=q[p][0]; lo.y=q[p][1]; lo.z=q[p][2]; lo.w=q[p][3];
      ushort4 hi; hi.x=q[p][4]; hi.y=q[p][5]; hi.z=q[p][6]; hi.w=q[p][7];
      *(ushort4*)(Asw + base + p*4096)     = lo;
      *(ushort4*)(Asw + base + p*4096 + 4) = hi;
    }
  }
}

// ---------------------------------------------------------------------------
// Kernel 3: split-K MFMA GEMM. BM=128, BN=128, BK=32, 256 thr = 4 waves.
// Wave wv owns cols [wv*32, wv*32+32): 8 mt x 2 nt tiles, acc = 64 f32/lane.
// A: direct global->register loads (fragment-ordered planes, L2-resident),
//    1-deep mt prefetch. B: fp32 LDS double-buffer via global_load_lds,
//    stage(s+1) issued before compute(s); one barrier per step.
// ---------------------------------------------------------------------------
__global__ __launch_bounds__(256, 2) void gemm_v3(
    const unsigned short* __restrict__ Asw, const float* __restrict__ B,
    float* __restrict__ part, const int nsteps) {
  __shared__ float Bsm[2][32][128];
  const int tid = threadIdx.x, lane = tid & 63, wv = tid >> 6;
  const int nb = blockIdx.x, ks = blockIdx.y;
  const int l15 = lane & 15, g = lane >> 4;
  const unsigned short* Ab = Asw + (size_t)ks * nsteps * 12288;
  const float* Bb = B + ((size_t)ks * nsteps * 32) * NH + (size_t)nb * 128;
  // staging address: rows wv*8 + i*2 + (lane>>5), cols (lane&31)*4
  const float* Bg = Bb + (size_t)(wv*8 + (lane >> 5)) * NH + (lane & 31) * 4;

  f32x4 acc[8][2];
  #pragma unroll
  for (int i = 0; i < 8; ++i)
    #pragma unroll
    for (int j = 0; j < 2; ++j) acc[i][j] = (f32x4){0.f, 0.f, 0.f, 0.f};

  // prologue: stage step 0 into buf 0
  #pragma unroll
  for (int i = 0; i < 4; ++i)
    gload16(Bg + (size_t)i*2*NH, &Bsm[0][wv*8 + i*2][0]);
  __syncthreads();

  int cur = 0;
  for (int s = 0; s < nsteps; ++s) {
    if (s + 1 < nsteps) {  // issue next-tile stage first (latency hides)
      const float* Bn = Bg + (size_t)(s+1)*32*NH;
      #pragma unroll
      for (int i = 0; i < 4; ++i)
        gload16(Bn + (size_t)i*2*NH, &Bsm[cur^1][wv*8 + i*2][0]);
    }
    // B fragments: lane holds B[k=g*8+e][nb*128 + wv*32 + nt*16 + l15]
    s16x8 bf0[2], bf1[2], bf2[2];
    #pragma unroll
    for (int nt = 0; nt < 2; ++nt) {
      #pragma unroll
      for (int e = 0; e < 8; ++e) {
        float xv = Bsm[cur][g*8 + e][wv*32 + nt*16 + l15];
        unsigned short q0, q1, q2; split3(xv, q0, q1, q2);
        bf0[nt][e] = (short)q0; bf1[nt][e] = (short)q1; bf2[nt][e] = (short)q2;
      }
    }
    const unsigned short* As = Ab + (size_t)s*12288 + lane*8;
    s16x8 a0n = *(const s16x8*)(As);
    s16x8 a1n = *(const s16x8*)(As + 4096);
    s16x8 a2n = *(const s16x8*)(As + 8192);
    #pragma unroll
    for (int mt = 0; mt < 8; ++mt) {
      const s16x8 a0 = a0n, a1 = a1n, a2 = a2n;
      if (mt < 7) {
        a0n = *(const s16x8*)(As + (mt+1)*512);
        a1n = *(const s16x8*)(As + 4096 + (mt+1)*512);
        a2n = *(const s16x8*)(As + 8192 + (mt+1)*512);
      }
      #pragma unroll
      for (int nt = 0; nt < 2; ++nt) {
        f32x4 cc = acc[mt][nt];
        cc = __builtin_amdgcn_mfma_f32_16x16x32_bf16(a0, bf0[nt], cc, 0, 0, 0);
        cc = __builtin_amdgcn_mfma_f32_16x16x32_bf16(a0, bf1[nt], cc, 0, 0, 0);
        cc = __builtin_amdgcn_mfma_f32_16x16x32_bf16(a1, bf0[nt], cc, 0, 0, 0);
        cc = __builtin_amdgcn_mfma_f32_16x16x32_bf16(a0, bf2[nt], cc, 0, 0, 0);
        cc = __builtin_amdgcn_mfma_f32_16x16x32_bf16(a1, bf1[nt], cc, 0, 0, 0);
        cc = __builtin_amdgcn_mfma_f32_16x16x32_bf16(a2, bf0[nt], cc, 0, 0, 0);
        acc[mt][nt] = cc;
      }
    }
    __syncthreads();   // drains stage(s+1); all waves done reading buf cur
    cur ^= 1;
  }
  // epilogue: C/D layout row=(lane>>4)*4+rr, col=lane&15
  float* Pb = part + (size_t)ks*N_BATCH*NH + (size_t)nb*128 + wv*32;
  #pragma unroll
  for (int mt = 0; mt < 8; ++mt)
    #pragma unroll
    for (int nt = 0; nt < 2; ++nt)
      #pragma unroll
      for (int rr = 0; rr < 4; ++rr)
        Pb[(size_t)(mt*16 + g*4 + rr)*NH + nt*16 + l15] = acc[mt][nt][rr];
}

// ---------------------------------------------------------------------------
// Kernel 4: reduce split-K partials + bias + relu -> fp32 [128][4096]
// ---------------------------------------------------------------------------
__global__ __launch_bounds__(256) void reduce_k(
    const float* __restrict__ part, const float* __restrict__ bias,
    float* __restrict__ outp, int KS) {
  const int idx = blockIdx.x*256 + threadIdx.x;     // float4 idx, 131072 total
  float4 s = ((const float4*)part)[idx];
  for (int k2 = 1; k2 < KS; ++k2) {
    float4 p = ((const float4*)part)[(size_t)k2*131072 + idx];
    s.x += p.x; s.y += p.y; s.z += p.z; s.w += p.w;
  }
  float4 bv = ((const float4*)bias)[idx & 1023];
  float4 o;
  o.x = fmaxf(s.x + bv.x, 0.f); o.y = fmaxf(s.y + bv.y, 0.f);
  o.z = fmaxf(s.z + bv.z, 0.f); o.w = fmaxf(s.w + bv.w, 0.f);
  ((float4*)outp)[idx] = o;
}

// ---------------------------------------------------------------------------
// Kernel 5: head — h2@Wcls (softmax) and h2@Wbox (bbox transform).
// ---------------------------------------------------------------------------
__global__ __launch_bounds__(128) void head_kernel(
    const float* __restrict__ h2, const float* __restrict__ Wcls,
    const float* __restrict__ Wbox, const int* __restrict__ rp,
    float* __restrict__ out) {
  const int n = blockIdx.x;
  const int tid = threadIdx.x;
  __shared__ float h2s[NH];
  __shared__ float logits[NCLS];
  __shared__ float red[2];
  for (int k = tid; k < NH; k += 128) h2s[k] = h2[(size_t)n*NH + k];
  __syncthreads();
  const bool is_cls = tid < NCLS;
  const bool is_box = (tid >= NCLS) && (tid < NCLS + NBOX);
  const float* W = is_cls ? (Wcls + tid) : (is_box ? (Wbox + (tid - NCLS)) : Wcls);
  const int stride = is_cls ? NCLS : (is_box ? NBOX : 0);
  float s0=0.f, s1=0.f, s2=0.f, s3=0.f;
  for (int k = 0; k < NH; k += 4) {
    s0 = fmaf(h2s[k+0], W[(size_t)(k+0)*stride], s0);
    s1 = fmaf(h2s[k+1], W[(size_t)(k+1)*stride], s1);
    s2 = fmaf(h2s[k+2], W[(size_t)(k+2)*stride], s2);
    s3 = fmaf(h2s[k+3], W[(size_t)(k+3)*stride], s3);
  }
  const float acc = (s0 + s1) + (s2 + s3);
  if (is_cls) logits[tid] = acc;
  __syncthreads();
  if (tid == 0) {
    float m = logits[0];
    for (int i = 1; i < NCLS; ++i) m = fmaxf(m, logits[i]);
    float s = 0.f;
    for (int i = 0; i < NCLS; ++i) s += expf(logits[i] - m);
    red[0] = m; red[1] = s;
  }
  __syncthreads();
  if (is_cls) {
    out[(size_t)n*NCLS + tid] = expf(logits[tid] - red[0]) / red[1];
  } else if (is_box) {
    const int j = tid - NCLS;
    const float t  = acc;
    const float rf = (float)rp[n*4+0];
    const float cf = (float)rp[n*4+1];
    const float wf = (float)rp[n*4+2];
    const float hf = (float)rp[n*4+3];
    float p;
    switch (j & 3) {
      case 0:  p = ceilf (__fmul_rn(__fadd_rn(__fmul_rn(wf, t), rf), 16.f)) - 1.f; break;
      case 1:  p = ceilf (__fmul_rn(__fadd_rn(__fmul_rn(hf, t), cf), 16.f)) - 1.f; break;
      case 2:  p = floorf(__fmul_rn(__fmul_rn(wf, expf(t)), 16.f)) + 1.f; break;
      default: p = floorf(__fmul_rn(__fmul_rn(hf, expf(t)), 16.f)) + 1.f; break;
    }
    out[(size_t)N_BATCH*NCLS + (size_t)n*NBOX + j] = p;
  }
}

// ---------------------------------------------------------------------------
extern "C" void kernel_launch(void* const* d_in, const int* in_sizes, int n_in,
                              void* d_out, int out_size, void* d_ws, size_t ws_size,
                              hipStream_t stream) {
  const float* x    = (const float*)d_in[0];
  const int*   rp   = (const int*)  d_in[1];
  const float* W1   = (const float*)d_in[2];
  const float* b1   = (const float*)d_in[3];
  const float* W2   = (const float*)d_in[4];
  const float* b2   = (const float*)d_in[5];
  const float* Wcls = (const float*)d_in[6];
  const float* Wbox = (const float*)d_in[7];
  float* out = (float*)d_out;

  // ws: flat 12.85MB | Asw1 19.27MB | Asw2 3.15MB | h1f 2.1MB | h2f 2.1MB | part
  char* wp = (char*)d_ws;
  float* flat = (float*)wp;           wp += (size_t)N_BATCH*K1*4;
  unsigned short* Asw1 = (unsigned short*)wp; wp += (size_t)STEPS1*24576;
  unsigned short* Asw2 = (unsigned short*)wp; wp += (size_t)STEPS2*24576;
  float* h1f = (float*)wp;            wp += (size_t)N_BATCH*NH*4;
  float* h2f = (float*)wp;            wp += (size_t)N_BATCH*NH*4;
  float* part = (float*)wp;
  const size_t fixed = (size_t)(wp - (char*)d_ws);
  const size_t slab = (size_t)N_BATCH*NH*4;       // 2 MB per partial
  int KS = 16;
  if (fixed + 16*slab > ws_size) KS = 8;
  if (fixed + (size_t)KS*slab > ws_size) KS = 4;

  pool_kernel<<<dim3(64, 128), 256, 0, stream>>>(x, rp, flat);
  convert_kernel<<<dim3(STEPS1), 256, 0, stream>>>(flat, Asw1, K1);

  gemm_v3<<<dim3(32, KS), 256, 0, stream>>>(Asw1, W1, part, STEPS1/KS);
  reduce_k<<<dim3(512), 256, 0, stream>>>(part, b1, h1f, KS);
  convert_kernel<<<dim3(STEPS2), 256, 0, stream>>>(h1f, Asw2, NH);

  gemm_v3<<<dim3(32, KS), 256, 0, stream>>>(Asw2, W2, part, STEPS2/KS);
  reduce_k<<<dim3(512), 256, 0, stream>>>(part, b2, h2f, KS);

  head_kernel<<<dim3(128), 128, 0, stream>>>(h2f, Wcls, Wbox, rp, out);
}

// Round 4
// 342.806 us; speedup vs baseline: 2.6615x; 1.6451x over previous
//
#include <hip/hip_runtime.h>
#include <hip/hip_bf16.h>
#include <math.h>

#define N_BATCH 128
#define C_CH    512
#define HF      38
#define WF      38
#define K1      25088   // 512*49
#define NH      4096
#define NCLS    21
#define NBOX    80
#define STEPS1  784     // K1/32
#define STEPS2  128     // NH/32

typedef __attribute__((ext_vector_type(8))) short s16x8;
typedef __attribute__((ext_vector_type(4))) float f32x4;

// fp32 -> 3x bf16 split (RNE): x ~= b0+b1+b2, residual ~ |x|*2^-25
__device__ __forceinline__ unsigned short bf_rne(float x) {
  unsigned u = __float_as_uint(x);
  return (unsigned short)((u + 0x7FFFu + ((u >> 16) & 1u)) >> 16);
}
__device__ __forceinline__ float bf2f(unsigned short b) {
  return __uint_as_float(((unsigned)b) << 16);
}
__device__ __forceinline__ void split3(float x, unsigned short& q0,
                                       unsigned short& q1, unsigned short& q2) {
  q0 = bf_rne(x); float r1 = x - bf2f(q0);
  q1 = bf_rne(r1); float r2 = r1 - bf2f(q1);
  q2 = bf_rne(r2);
}

__device__ __forceinline__ void gload16(const void* g, void* l) {
  __builtin_amdgcn_global_load_lds(
      (const __attribute__((address_space(1))) unsigned int*)g,
      (__attribute__((address_space(3))) unsigned int*)l, 16, 0, 0);
}

// ---------------------------------------------------------------------------
// Kernel 1: ROI crop + adaptive 7x7 maxpool -> flat fp32 [128][K1]
// ---------------------------------------------------------------------------
__global__ __launch_bounds__(256) void pool_kernel(
    const float* __restrict__ x, const int* __restrict__ rp,
    float* __restrict__ flat) {
  const int n = blockIdx.y, cb = blockIdx.x, tid = threadIdx.x;
  const int r = rp[n*4+0], c = rp[n*4+1], w = rp[n*4+2], h = rp[n*4+3];
  __shared__ float tile[8][24][25];
  const int ch = tid >> 5, l32 = tid & 31;
  const float* xc = x + (((size_t)(n*C_CH + cb*8 + ch))*HF + c)*WF + r;
  for (int y = 0; y < h; ++y)
    for (int xx = l32; xx < w; xx += 32)
      tile[ch][y][xx] = xc[y*WF + xx];
  __syncthreads();
  for (int o = tid; o < 8*49; o += 256) {
    int ch2 = o / 49, ij = o - ch2*49, i = ij / 7, j = ij - i*7;
    int rs = (i*h)/7, re = ((i+1)*h + 6)/7;
    int cs = (j*w)/7, ce = ((j+1)*w + 6)/7;
    float m = -INFINITY;
    for (int y = rs; y < re; ++y)
      for (int xx = cs; xx < ce; ++xx)
        m = fmaxf(m, tile[ch2][y][xx]);
    flat[(size_t)n*K1 + (cb*8+ch2)*49 + ij] = m;
  }
}

// ---------------------------------------------------------------------------
// Kernel 2: fp32 [128][ld] -> 3 bf16 planes in MFMA fragment order.
// ---------------------------------------------------------------------------
__global__ __launch_bounds__(256) void convert_kernel(
    const float* __restrict__ flat, unsigned short* __restrict__ Asw, int ld) {
  const int S = blockIdx.x, t = threadIdx.x;
  const int mt = t >> 5, g2 = (t >> 4) & 1, mlo = t & 15;
  #pragma unroll
  for (int gg = 0; gg < 2; ++gg) {
    const int g = g2 + gg*2;
    const float* src = flat + (size_t)(mt*16 + mlo)*ld + S*32 + g*8;
    float v[8];
    *(float4*)&v[0] = *(const float4*)src;
    *(float4*)&v[4] = *(const float4*)(src + 4);
    unsigned short q[3][8];
    #pragma unroll
    for (int e = 0; e < 8; ++e) split3(v[e], q[0][e], q[1][e], q[2][e]);
    size_t base = (size_t)S*12288 + mt*512 + (size_t)(g*16 + mlo)*8;
    #pragma unroll
    for (int p = 0; p < 3; ++p) {
      ushort4 lo; lo.x=q[p][0]; lo.y=q[p][1]; lo.z=q[p][2]; lo.w=q[p][3];
      ushort4 hi; hi.x=q[p][4]; hi.y=q[p][5]; hi.z=q[p][6]; hi.w=q[p][7];
      *(ushort4*)(Asw + base + p*4096)     = lo;
      *(ushort4*)(Asw + base + p*4096 + 4) = hi;
    }
  }
}

// ---------------------------------------------------------------------------
// Kernel 3: split-K MFMA GEMM. BM=128, BN=128, BK=32, 256 thr = 4 waves.
// (unchanged from round 3)
// ---------------------------------------------------------------------------
__global__ __launch_bounds__(256, 2) void gemm_v3(
    const unsigned short* __restrict__ Asw, const float* __restrict__ B,
    float* __restrict__ part, const int nsteps) {
  __shared__ float Bsm[2][32][128];
  const int tid = threadIdx.x, lane = tid & 63, wv = tid >> 6;
  const int nb = blockIdx.x, ks = blockIdx.y;
  const int l15 = lane & 15, g = lane >> 4;
  const unsigned short* Ab = Asw + (size_t)ks * nsteps * 12288;
  const float* Bb = B + ((size_t)ks * nsteps * 32) * NH + (size_t)nb * 128;
  const float* Bg = Bb + (size_t)(wv*8 + (lane >> 5)) * NH + (lane & 31) * 4;

  f32x4 acc[8][2];
  #pragma unroll
  for (int i = 0; i < 8; ++i)
    #pragma unroll
    for (int j = 0; j < 2; ++j) acc[i][j] = (f32x4){0.f, 0.f, 0.f, 0.f};

  #pragma unroll
  for (int i = 0; i < 4; ++i)
    gload16(Bg + (size_t)i*2*NH, &Bsm[0][wv*8 + i*2][0]);
  __syncthreads();

  int cur = 0;
  for (int s = 0; s < nsteps; ++s) {
    if (s + 1 < nsteps) {
      const float* Bn = Bg + (size_t)(s+1)*32*NH;
      #pragma unroll
      for (int i = 0; i < 4; ++i)
        gload16(Bn + (size_t)i*2*NH, &Bsm[cur^1][wv*8 + i*2][0]);
    }
    s16x8 bf0[2], bf1[2], bf2[2];
    #pragma unroll
    for (int nt = 0; nt < 2; ++nt) {
      #pragma unroll
      for (int e = 0; e < 8; ++e) {
        float xv = Bsm[cur][g*8 + e][wv*32 + nt*16 + l15];
        unsigned short q0, q1, q2; split3(xv, q0, q1, q2);
        bf0[nt][e] = (short)q0; bf1[nt][e] = (short)q1; bf2[nt][e] = (short)q2;
      }
    }
    const unsigned short* As = Ab + (size_t)s*12288 + lane*8;
    s16x8 a0n = *(const s16x8*)(As);
    s16x8 a1n = *(const s16x8*)(As + 4096);
    s16x8 a2n = *(const s16x8*)(As + 8192);
    #pragma unroll
    for (int mt = 0; mt < 8; ++mt) {
      const s16x8 a0 = a0n, a1 = a1n, a2 = a2n;
      if (mt < 7) {
        a0n = *(const s16x8*)(As + (mt+1)*512);
        a1n = *(const s16x8*)(As + 4096 + (mt+1)*512);
        a2n = *(const s16x8*)(As + 8192 + (mt+1)*512);
      }
      #pragma unroll
      for (int nt = 0; nt < 2; ++nt) {
        f32x4 cc = acc[mt][nt];
        cc = __builtin_amdgcn_mfma_f32_16x16x32_bf16(a0, bf0[nt], cc, 0, 0, 0);
        cc = __builtin_amdgcn_mfma_f32_16x16x32_bf16(a0, bf1[nt], cc, 0, 0, 0);
        cc = __builtin_amdgcn_mfma_f32_16x16x32_bf16(a1, bf0[nt], cc, 0, 0, 0);
        cc = __builtin_amdgcn_mfma_f32_16x16x32_bf16(a0, bf2[nt], cc, 0, 0, 0);
        cc = __builtin_amdgcn_mfma_f32_16x16x32_bf16(a1, bf1[nt], cc, 0, 0, 0);
        cc = __builtin_amdgcn_mfma_f32_16x16x32_bf16(a2, bf0[nt], cc, 0, 0, 0);
        acc[mt][nt] = cc;
      }
    }
    __syncthreads();
    cur ^= 1;
  }
  float* Pb = part + (size_t)ks*N_BATCH*NH + (size_t)nb*128 + wv*32;
  #pragma unroll
  for (int mt = 0; mt < 8; ++mt)
    #pragma unroll
    for (int nt = 0; nt < 2; ++nt)
      #pragma unroll
      for (int rr = 0; rr < 4; ++rr)
        Pb[(size_t)(mt*16 + g*4 + rr)*NH + nt*16 + l15] = acc[mt][nt][rr];
}

// ---------------------------------------------------------------------------
// Kernel 4: reduce split-K partials + bias + relu -> fp32 [128][4096]
// ---------------------------------------------------------------------------
__global__ __launch_bounds__(256) void reduce_k(
    const float* __restrict__ part, const float* __restrict__ bias,
    float* __restrict__ outp, int KS) {
  const int idx = blockIdx.x*256 + threadIdx.x;
  float4 s = ((const float4*)part)[idx];
  for (int k2 = 1; k2 < KS; ++k2) {
    float4 p = ((const float4*)part)[(size_t)k2*131072 + idx];
    s.x += p.x; s.y += p.y; s.z += p.z; s.w += p.w;
  }
  float4 bv = ((const float4*)bias)[idx & 1023];
  float4 o;
  o.x = fmaxf(s.x + bv.x, 0.f); o.y = fmaxf(s.y + bv.y, 0.f);
  o.z = fmaxf(s.z + bv.z, 0.f); o.w = fmaxf(s.w + bv.w, 0.f);
  ((float4*)outp)[idx] = o;
}

// ---------------------------------------------------------------------------
// Kernel 5a: transpose Wcls|Wbox into WT[101][4096] (contiguous rows).
// Reads strided (one column per block, L2-served), writes coalesced.
// ---------------------------------------------------------------------------
__global__ __launch_bounds__(256) void head_transpose(
    const float* __restrict__ Wcls, const float* __restrict__ Wbox,
    float* __restrict__ WT) {
  const int c = blockIdx.x;
  const float* src; int stride;
  if (c < NCLS) { src = Wcls + c; stride = NCLS; }
  else          { src = Wbox + (c - NCLS); stride = NBOX; }
  for (int k = threadIdx.x; k < NH; k += 256)
    WT[(size_t)c*NH + k] = src[(size_t)k*stride];
}

// ---------------------------------------------------------------------------
// Kernel 5b: one wave per (n, col): coalesced float4 dot over K=4096,
// butterfly shuffle reduce. 12928 waves = ~50/CU.
// ---------------------------------------------------------------------------
__global__ __launch_bounds__(256) void head_dots(
    const float* __restrict__ h2, const float* __restrict__ WT,
    float* __restrict__ hout) {
  const int n = blockIdx.y;
  const int wv = threadIdx.x >> 6, lane = threadIdx.x & 63;
  const int c = blockIdx.x * 4 + wv;
  if (c >= NCLS + NBOX) return;
  const float4* hp = (const float4*)(h2 + (size_t)n*NH);
  const float4* wp = (const float4*)(WT + (size_t)c*NH);
  float s0=0.f, s1=0.f, s2=0.f, s3=0.f;
  #pragma unroll
  for (int it = 0; it < 16; ++it) {
    float4 a = hp[it*64 + lane];
    float4 b = wp[it*64 + lane];
    s0 = fmaf(a.x, b.x, s0); s1 = fmaf(a.y, b.y, s1);
    s2 = fmaf(a.z, b.z, s2); s3 = fmaf(a.w, b.w, s3);
  }
  float v = (s0 + s1) + (s2 + s3);
  #pragma unroll
  for (int m = 32; m >= 1; m >>= 1) v += __shfl_xor(v, m, 64);
  if (lane == 0) hout[n*128 + c] = v;
}

// ---------------------------------------------------------------------------
// Kernel 5c: softmax(21) + bbox(80) from stored dots.
// ---------------------------------------------------------------------------
__global__ __launch_bounds__(128) void head_final(
    const float* __restrict__ hout, const int* __restrict__ rp,
    float* __restrict__ out) {
  const int n = blockIdx.x, tid = threadIdx.x;
  __shared__ float logits[NCLS];
  __shared__ float red[2];
  if (tid < NCLS) logits[tid] = hout[n*128 + tid];
  __syncthreads();
  if (tid == 0) {
    float m = logits[0];
    for (int i = 1; i < NCLS; ++i) m = fmaxf(m, logits[i]);
    float s = 0.f;
    for (int i = 0; i < NCLS; ++i) s += expf(logits[i] - m);
    red[0] = m; red[1] = s;
  }
  __syncthreads();
  if (tid < NCLS) {
    out[(size_t)n*NCLS + tid] = expf(logits[tid] - red[0]) / red[1];
  } else if (tid < NCLS + NBOX) {
    const int j = tid - NCLS;
    const float t  = hout[n*128 + tid];
    const float rf = (float)rp[n*4+0];
    const float cf = (float)rp[n*4+1];
    const float wf = (float)rp[n*4+2];
    const float hf = (float)rp[n*4+3];
    float p;
    switch (j & 3) {
      case 0:  p = ceilf (__fmul_rn(__fadd_rn(__fmul_rn(wf, t), rf), 16.f)) - 1.f; break;
      case 1:  p = ceilf (__fmul_rn(__fadd_rn(__fmul_rn(hf, t), cf), 16.f)) - 1.f; break;
      case 2:  p = floorf(__fmul_rn(__fmul_rn(wf, expf(t)), 16.f)) + 1.f; break;
      default: p = floorf(__fmul_rn(__fmul_rn(hf, expf(t)), 16.f)) + 1.f; break;
    }
    out[(size_t)N_BATCH*NCLS + (size_t)n*NBOX + j] = p;
  }
}

// ---------------------------------------------------------------------------
extern "C" void kernel_launch(void* const* d_in, const int* in_sizes, int n_in,
                              void* d_out, int out_size, void* d_ws, size_t ws_size,
                              hipStream_t stream) {
  const float* x    = (const float*)d_in[0];
  const int*   rp   = (const int*)  d_in[1];
  const float* W1   = (const float*)d_in[2];
  const float* b1   = (const float*)d_in[3];
  const float* W2   = (const float*)d_in[4];
  const float* b2   = (const float*)d_in[5];
  const float* Wcls = (const float*)d_in[6];
  const float* Wbox = (const float*)d_in[7];
  float* out = (float*)d_out;

  // ws: flat | Asw1 | Asw2 | h1f | h2f | WT | hout | part
  char* wp = (char*)d_ws;
  float* flat = (float*)wp;           wp += (size_t)N_BATCH*K1*4;
  unsigned short* Asw1 = (unsigned short*)wp; wp += (size_t)STEPS1*24576;
  unsigned short* Asw2 = (unsigned short*)wp; wp += (size_t)STEPS2*24576;
  float* h1f = (float*)wp;            wp += (size_t)N_BATCH*NH*4;
  float* h2f = (float*)wp;            wp += (size_t)N_BATCH*NH*4;
  float* WT  = (float*)wp;            wp += (size_t)(NCLS+NBOX)*NH*4;
  float* hout = (float*)wp;           wp += (size_t)N_BATCH*128*4;
  float* part = (float*)wp;
  const size_t fixed = (size_t)(wp - (char*)d_ws);
  const size_t slab = (size_t)N_BATCH*NH*4;       // 2 MB per partial
  int KS = 16;
  if (fixed + 16*slab > ws_size) KS = 8;
  if (fixed + (size_t)KS*slab > ws_size) KS = 4;

  pool_kernel<<<dim3(64, 128), 256, 0, stream>>>(x, rp, flat);
  convert_kernel<<<dim3(STEPS1), 256, 0, stream>>>(flat, Asw1, K1);
  head_transpose<<<dim3(NCLS + NBOX), 256, 0, stream>>>(Wcls, Wbox, WT);

  gemm_v3<<<dim3(32, KS), 256, 0, stream>>>(Asw1, W1, part, STEPS1/KS);
  reduce_k<<<dim3(512), 256, 0, stream>>>(part, b1, h1f, KS);
  convert_kernel<<<dim3(STEPS2), 256, 0, stream>>>(h1f, Asw2, NH);

  gemm_v3<<<dim3(32, KS), 256, 0, stream>>>(Asw2, W2, part, STEPS2/KS);
  reduce_k<<<dim3(512), 256, 0, stream>>>(part, b2, h2f, KS);

  head_dots<<<dim3(26, 128), 256, 0, stream>>>(h2f, WT, hout);
  head_final<<<dim3(128), 128, 0, stream>>>(hout, rp, out);
}